// Round 1
// baseline (134.903 us; speedup 1.0000x reference)
//
#include <hip/hip_runtime.h>
#include <hip/hip_bf16.h>
#include <math.h>

#define NN 8192
#define DD 64

typedef __bf16 bf16x8 __attribute__((ext_vector_type(8)));
typedef float f32x4 __attribute__((ext_vector_type(4)));

#if defined(__has_builtin)
#if __has_builtin(__builtin_amdgcn_exp2f)
#define EXP2F __builtin_amdgcn_exp2f
#endif
#endif
#ifndef EXP2F
#define EXP2F exp2f
#endif

// ws layout:
//   [0,        1048576)  Xb  bf16 [8192][64]
//   [1048576,  2097152)  Zb  bf16 [8192][64]
//   [2097152, +32768)    na  f32  [8192]   ( = -log2(e) * ||x_i||^2 )
//   [+32768,  +65536)    nb  f32  [8192]
//   [+65536,  +65548)    S   f32  [3]      (sum exp(-d2) for xx, zz, xz)

__global__ void prep_kernel(const float* __restrict__ X, const float* __restrict__ Z,
                            __hip_bfloat16* __restrict__ Xb, __hip_bfloat16* __restrict__ Zb,
                            float* __restrict__ na, float* __restrict__ nb,
                            float* __restrict__ S) {
    int gw = (blockIdx.x * blockDim.x + threadIdx.x) >> 6;  // global wave = row index in [0, 2N)
    int lane = threadIdx.x & 63;
    if (gw < 2 * NN) {
        const float* src = (gw < NN) ? (X + (size_t)gw * DD) : (Z + (size_t)(gw - NN) * DD);
        float v = src[lane];
        __hip_bfloat16 h = __float2bfloat16(v);
        float xr = __bfloat162float(h);
        __hip_bfloat16* dst = (gw < NN) ? (Xb + (size_t)gw * DD) : (Zb + (size_t)(gw - NN) * DD);
        dst[lane] = h;
        float s = xr * xr;
        #pragma unroll
        for (int off = 32; off; off >>= 1) s += __shfl_xor(s, off, 64);
        if (lane == 0) {
            if (gw < NN) na[gw] = -1.4426950408889634f * s;
            else         nb[gw - NN] = -1.4426950408889634f * s;
        }
    }
    if (blockIdx.x == 0 && threadIdx.x < 3) S[threadIdx.x] = 0.f;
}

// block = 256 threads (4 waves as 2x2), block tile 128x128, wave tile 64x64.
// grid = (N/128, N/128, 3); combo z: 0=XX, 1=ZZ, 2=XZ. Symmetric combos only
// compute bj>=bi; off-diagonal blocks count double, diagonal blocks weight
// per element (i<j: 2, i==j: 1, i>j: 0).
__global__ __launch_bounds__(256) void mmd_kernel(
        const __hip_bfloat16* __restrict__ Xb, const __hip_bfloat16* __restrict__ Zb,
        const float* __restrict__ na, const float* __restrict__ nb,
        float* __restrict__ S) {
    int combo = blockIdx.z;
    const __bf16 *A, *B;
    const float *sa, *sb;
    bool sym = (combo != 2);
    if (combo == 0)      { A = (const __bf16*)Xb; B = (const __bf16*)Xb; sa = na; sb = na; }
    else if (combo == 1) { A = (const __bf16*)Zb; B = (const __bf16*)Zb; sa = nb; sb = nb; }
    else                 { A = (const __bf16*)Xb; B = (const __bf16*)Zb; sa = na; sb = nb; }

    int bi = blockIdx.x, bj = blockIdx.y;
    if (sym && bj < bi) return;
    float blockScale = (sym && bj > bi) ? 2.f : 1.f;
    bool diag = sym && (bi == bj);

    int tid = threadIdx.x;
    int wave = tid >> 6, lane = tid & 63;
    int wr = wave >> 1, wc = wave & 1;
    int row0 = bi * 128 + wr * 64;   // wave-tile origin (global row)
    int col0 = bj * 128 + wc * 64;   // wave-tile origin (global col)

    int lm = lane & 15;   // A-frag row / B-frag col / C col (within 16)
    int lk = lane >> 4;   // k-block (8 elems each)

    // Load all fragments for K=64 (two k-steps of 32), then MFMA.
    bf16x8 af[2][4], bfr[2][4];
    #pragma unroll
    for (int ks = 0; ks < 2; ++ks) {
        #pragma unroll
        for (int t = 0; t < 4; ++t) {
            af[ks][t]  = *(const bf16x8*)(A + (size_t)(row0 + t * 16 + lm) * DD + ks * 32 + lk * 8);
            bfr[ks][t] = *(const bf16x8*)(B + (size_t)(col0 + t * 16 + lm) * DD + ks * 32 + lk * 8);
        }
    }
    f32x4 acc[4][4] = {};
    #pragma unroll
    for (int ks = 0; ks < 2; ++ks)
        #pragma unroll
        for (int rt = 0; rt < 4; ++rt)
            #pragma unroll
            for (int ct = 0; ct < 4; ++ct)
                acc[rt][ct] = __builtin_amdgcn_mfma_f32_16x16x32_bf16(
                    af[ks][rt], bfr[ks][ct], acc[rt][ct], 0, 0, 0);

    // Epilogue: arg = -log2(e)*d2 = 2*log2(e)*dot + na_i + nb_j, clamp <= 0, sum exp2(arg).
    const float C2 = 2.8853900817779268f;  // 2*log2(e)
    float nbv[4], nav[4][4];
    #pragma unroll
    for (int ct = 0; ct < 4; ++ct) nbv[ct] = sb[col0 + ct * 16 + lm];
    #pragma unroll
    for (int rt = 0; rt < 4; ++rt)
        #pragma unroll
        for (int r = 0; r < 4; ++r) nav[rt][r] = sa[row0 + rt * 16 + lk * 4 + r];

    float lsum = 0.f;
    if (diag) {
        #pragma unroll
        for (int rt = 0; rt < 4; ++rt)
            #pragma unroll
            for (int ct = 0; ct < 4; ++ct)
                #pragma unroll
                for (int r = 0; r < 4; ++r) {
                    float arg = fmaf(acc[rt][ct][r], C2, nav[rt][r] + nbv[ct]);
                    float t = EXP2F(fminf(arg, 0.f));
                    int grow = row0 + rt * 16 + lk * 4 + r;
                    int gcol = col0 + ct * 16 + lm;
                    t = (grow < gcol) ? 2.f * t : ((grow == gcol) ? t : 0.f);
                    lsum += t;
                }
    } else {
        #pragma unroll
        for (int rt = 0; rt < 4; ++rt)
            #pragma unroll
            for (int ct = 0; ct < 4; ++ct)
                #pragma unroll
                for (int r = 0; r < 4; ++r) {
                    float arg = fmaf(acc[rt][ct][r], C2, nav[rt][r] + nbv[ct]);
                    lsum += EXP2F(fminf(arg, 0.f));
                }
    }

    // block reduction -> one atomic per block
    #pragma unroll
    for (int off = 32; off; off >>= 1) lsum += __shfl_xor(lsum, off, 64);
    __shared__ float wsum[4];
    if (lane == 0) wsum[wave] = lsum;
    __syncthreads();
    if (tid == 0) {
        float s = (wsum[0] + wsum[1]) + (wsum[2] + wsum[3]);
        atomicAdd(&S[combo], s * blockScale);
    }
}

__global__ void final_kernel(const float* __restrict__ S, float* __restrict__ out) {
    if (threadIdx.x == 0 && blockIdx.x == 0) {
        double inv = 1.0 / ((double)NN * (double)NN * 2.5066282746310002);  // N^2 * sqrt(2*pi)
        double mxx = (double)S[0] * inv;
        double mzz = (double)S[1] * inv;
        double mxz = (double)S[2] * inv;
        double v = log(sqrt(mxx * mzz + 1e-5) / (mxz + 1e-5));
        out[0] = (float)v;
    }
}

extern "C" void kernel_launch(void* const* d_in, const int* in_sizes, int n_in,
                              void* d_out, int out_size, void* d_ws, size_t ws_size,
                              hipStream_t stream) {
    const float* X = (const float*)d_in[0];
    const float* Z = (const float*)d_in[1];
    char* ws = (char*)d_ws;
    __hip_bfloat16* Xb = (__hip_bfloat16*)(ws);
    __hip_bfloat16* Zb = (__hip_bfloat16*)(ws + 1048576);
    float* na = (float*)(ws + 2097152);
    float* nb = (float*)(ws + 2097152 + 32768);
    float* S  = (float*)(ws + 2097152 + 65536);

    hipLaunchKernelGGL(prep_kernel, dim3((2 * NN) / 4), dim3(256), 0, stream,
                       X, Z, Xb, Zb, na, nb, S);
    dim3 grid(NN / 128, NN / 128, 3);
    hipLaunchKernelGGL(mmd_kernel, grid, dim3(256), 0, stream, Xb, Zb, na, nb, S);
    hipLaunchKernelGGL(final_kernel, dim3(1), dim3(1), 0, stream, S, (float*)d_out);
}

// Round 2
// 70.509 us; speedup vs baseline: 1.9133x; 1.9133x over previous
//
#include <hip/hip_runtime.h>
#include <hip/hip_bf16.h>
#include <math.h>

#define NN 8192
#define DD 64
#define TILES_SYM 2080          // 64*65/2 per symmetric combo
#define TILES_TOTAL 8256        // 2*2080 + 4096
#define TILES_PER_BLOCK 8
#define NBLOCKS (TILES_TOTAL / TILES_PER_BLOCK)   // 1032

typedef __bf16 bf16x8 __attribute__((ext_vector_type(8)));
typedef float f32x4 __attribute__((ext_vector_type(4)));

#if defined(__has_builtin)
#if __has_builtin(__builtin_amdgcn_exp2f)
#define EXP2F __builtin_amdgcn_exp2f
#endif
#endif
#ifndef EXP2F
#define EXP2F exp2f
#endif

// ws layout:
//   [0,        1048576)  Xb  bf16 [8192][64]
//   [1048576,  2097152)  Zb  bf16 [8192][64]
//   [2097152, +32768)    na  f32  [8192]   ( = -log2(e) * ||x_i||^2 )
//   [+32768,  +65536)    nb  f32  [8192]
//   [+65536,  +65548)    S   f32  [3]      (sum exp(-d2) for xx, zz, xz)

__global__ void prep_kernel(const float* __restrict__ X, const float* __restrict__ Z,
                            __hip_bfloat16* __restrict__ Xb, __hip_bfloat16* __restrict__ Zb,
                            float* __restrict__ na, float* __restrict__ nb,
                            float* __restrict__ S) {
    int gw = (blockIdx.x * blockDim.x + threadIdx.x) >> 6;  // global wave = row index in [0, 2N)
    int lane = threadIdx.x & 63;
    if (gw < 2 * NN) {
        const float* src = (gw < NN) ? (X + (size_t)gw * DD) : (Z + (size_t)(gw - NN) * DD);
        float v = src[lane];
        __hip_bfloat16 h = __float2bfloat16(v);
        float xr = __bfloat162float(h);
        __hip_bfloat16* dst = (gw < NN) ? (Xb + (size_t)gw * DD) : (Zb + (size_t)(gw - NN) * DD);
        dst[lane] = h;
        float s = xr * xr;
        #pragma unroll
        for (int off = 32; off; off >>= 1) s += __shfl_xor(s, off, 64);
        if (lane == 0) {
            if (gw < NN) na[gw] = -1.4426950408889634f * s;
            else         nb[gw - NN] = -1.4426950408889634f * s;
        }
    }
    if (blockIdx.x == 0 && threadIdx.x < 3) S[threadIdx.x] = 0.f;
}

// Flat tile enumeration over live tiles only:
//   [0, 2080)        XX, upper triangle (bj >= bi)
//   [2080, 4160)     ZZ, upper triangle
//   [4160, 8256)     XZ, full 64x64
// Each block walks TILES_PER_BLOCK consecutive tiles; A-frags/row-norms are
// reloaded only on row change; one atomic per block per combo encountered
// (chunks are combo-aligned: 2080 and 4160 are divisible by 8).
__global__ __launch_bounds__(256) void mmd_kernel(
        const __hip_bfloat16* __restrict__ Xb, const __hip_bfloat16* __restrict__ Zb,
        const float* __restrict__ na, const float* __restrict__ nb,
        float* __restrict__ S) {
    int tid = threadIdx.x;
    int wave = tid >> 6, lane = tid & 63;
    int wr = wave >> 1, wc = wave & 1;
    int lm = lane & 15;   // A-frag row / B-frag col / C col (within 16)
    int lk = lane >> 4;   // k-group of 8 / C row group of 4
    __shared__ float wsum[4];

    const __bf16 *A = (const __bf16*)Xb, *B = (const __bf16*)Xb;
    const float *sa = na, *sb = na;
    bool sym = true;
    int curCombo = -1, curBi = -1;
    float lsum = 0.f;
    bf16x8 af[2][4];
    float nav[4][4];
    const float C2 = 2.8853900817779268f;  // 2*log2(e)

    int t0 = blockIdx.x * TILES_PER_BLOCK;
    for (int t = t0; t < t0 + TILES_PER_BLOCK; ++t) {
        // ---- map flat id -> (combo, bi, bj) ----
        int combo, bi, bj;
        if (t < 2 * TILES_SYM) {
            combo = (t < TILES_SYM) ? 0 : 1;
            int tt = (t < TILES_SYM) ? t : t - TILES_SYM;
            int rr = (int)((129.0f - sqrtf(16641.0f - 8.0f * (float)tt)) * 0.5f);
            if (rr < 0) rr = 0;
            while (rr > 0 && rr * (129 - rr) / 2 > tt) --rr;
            while ((rr + 1) * (128 - rr) / 2 <= tt) ++rr;
            bi = rr;
            bj = rr + (tt - rr * (129 - rr) / 2);
        } else {
            combo = 2;
            int rem = t - 2 * TILES_SYM;
            bi = rem >> 6;
            bj = rem & 63;
        }

        if (combo != curCombo) {
            if (curCombo >= 0) {
                // flush lsum for previous combo
                float s = lsum;
                #pragma unroll
                for (int off = 32; off; off >>= 1) s += __shfl_xor(s, off, 64);
                if (lane == 0) wsum[wave] = s;
                __syncthreads();
                if (tid == 0) atomicAdd(&S[curCombo], (wsum[0] + wsum[1]) + (wsum[2] + wsum[3]));
                __syncthreads();
                lsum = 0.f;
            }
            if (combo == 0)      { A = (const __bf16*)Xb; B = (const __bf16*)Xb; sa = na; sb = na; }
            else if (combo == 1) { A = (const __bf16*)Zb; B = (const __bf16*)Zb; sa = nb; sb = nb; }
            else                 { A = (const __bf16*)Xb; B = (const __bf16*)Zb; sa = na; sb = nb; }
            sym = (combo != 2);
            curCombo = combo;
            curBi = -1;
        }

        int row0 = bi * 128 + wr * 64;
        int col0 = bj * 128 + wc * 64;

        if (bi != curBi) {
            curBi = bi;
            #pragma unroll
            for (int ks = 0; ks < 2; ++ks)
                #pragma unroll
                for (int rt = 0; rt < 4; ++rt)
                    af[ks][rt] = *(const bf16x8*)(A + (size_t)(row0 + rt * 16 + lm) * DD + ks * 32 + lk * 8);
            #pragma unroll
            for (int rt = 0; rt < 4; ++rt)
                #pragma unroll
                for (int r = 0; r < 4; ++r)
                    nav[rt][r] = sa[row0 + rt * 16 + lk * 4 + r];
        }

        bf16x8 bfr[2][4];
        float nbv[4];
        #pragma unroll
        for (int ks = 0; ks < 2; ++ks)
            #pragma unroll
            for (int ct = 0; ct < 4; ++ct)
                bfr[ks][ct] = *(const bf16x8*)(B + (size_t)(col0 + ct * 16 + lm) * DD + ks * 32 + lk * 8);
        #pragma unroll
        for (int ct = 0; ct < 4; ++ct) nbv[ct] = sb[col0 + ct * 16 + lm];

        f32x4 acc[4][4] = {};
        #pragma unroll
        for (int ks = 0; ks < 2; ++ks)
            #pragma unroll
            for (int rt = 0; rt < 4; ++rt)
                #pragma unroll
                for (int ct = 0; ct < 4; ++ct)
                    acc[rt][ct] = __builtin_amdgcn_mfma_f32_16x16x32_bf16(
                        af[ks][rt], bfr[ks][ct], acc[rt][ct], 0, 0, 0);

        // ---- epilogue: arg = -log2e*d2; skip exp2 when whole fragment < 2^-30 ----
        bool diag = sym && (bi == bj);
        float tileScale = (sym && bj > bi) ? 2.f : 1.f;
        #pragma unroll
        for (int rt = 0; rt < 4; ++rt) {
            #pragma unroll
            for (int ct = 0; ct < 4; ++ct) {
                float base = nbv[ct];
                float a0 = fmaf(acc[rt][ct][0], C2, nav[rt][0] + base);
                float a1 = fmaf(acc[rt][ct][1], C2, nav[rt][1] + base);
                float a2 = fmaf(acc[rt][ct][2], C2, nav[rt][2] + base);
                float a3 = fmaf(acc[rt][ct][3], C2, nav[rt][3] + base);
                float mx = fmaxf(fmaxf(a0, a1), fmaxf(a2, a3));
                if (__any(mx > -30.f)) {
                    float e0 = EXP2F(fminf(a0, 0.f));
                    float e1 = EXP2F(fminf(a1, 0.f));
                    float e2 = EXP2F(fminf(a2, 0.f));
                    float e3 = EXP2F(fminf(a3, 0.f));
                    if (diag) {
                        int gcol = col0 + ct * 16 + lm;
                        int gr = row0 + rt * 16 + lk * 4;
                        e0 *= (gr + 0 < gcol) ? 2.f : ((gr + 0 == gcol) ? 1.f : 0.f);
                        e1 *= (gr + 1 < gcol) ? 2.f : ((gr + 1 == gcol) ? 1.f : 0.f);
                        e2 *= (gr + 2 < gcol) ? 2.f : ((gr + 2 == gcol) ? 1.f : 0.f);
                        e3 *= (gr + 3 < gcol) ? 2.f : ((gr + 3 == gcol) ? 1.f : 0.f);
                        lsum += (e0 + e1) + (e2 + e3);
                    } else {
                        lsum += tileScale * ((e0 + e1) + (e2 + e3));
                    }
                }
            }
        }
    }

    // final flush
    {
        float s = lsum;
        #pragma unroll
        for (int off = 32; off; off >>= 1) s += __shfl_xor(s, off, 64);
        if (lane == 0) wsum[wave] = s;
        __syncthreads();
        if (tid == 0) atomicAdd(&S[curCombo], (wsum[0] + wsum[1]) + (wsum[2] + wsum[3]));
    }
}

__global__ void final_kernel(const float* __restrict__ S, float* __restrict__ out) {
    if (threadIdx.x == 0 && blockIdx.x == 0) {
        double inv = 1.0 / ((double)NN * (double)NN * 2.5066282746310002);  // N^2 * sqrt(2*pi)
        double mxx = (double)S[0] * inv;
        double mzz = (double)S[1] * inv;
        double mxz = (double)S[2] * inv;
        double v = log(sqrt(mxx * mzz + 1e-5) / (mxz + 1e-5));
        out[0] = (float)v;
    }
}

extern "C" void kernel_launch(void* const* d_in, const int* in_sizes, int n_in,
                              void* d_out, int out_size, void* d_ws, size_t ws_size,
                              hipStream_t stream) {
    const float* X = (const float*)d_in[0];
    const float* Z = (const float*)d_in[1];
    char* ws = (char*)d_ws;
    __hip_bfloat16* Xb = (__hip_bfloat16*)(ws);
    __hip_bfloat16* Zb = (__hip_bfloat16*)(ws + 1048576);
    float* na = (float*)(ws + 2097152);
    float* nb = (float*)(ws + 2097152 + 32768);
    float* S  = (float*)(ws + 2097152 + 65536);

    hipLaunchKernelGGL(prep_kernel, dim3((2 * NN) / 4), dim3(256), 0, stream,
                       X, Z, Xb, Zb, na, nb, S);
    hipLaunchKernelGGL(mmd_kernel, dim3(NBLOCKS), dim3(256), 0, stream, Xb, Zb, na, nb, S);
    hipLaunchKernelGGL(final_kernel, dim3(1), dim3(1), 0, stream, S, (float*)d_out);
}

// Round 3
// 64.101 us; speedup vs baseline: 2.1045x; 1.1000x over previous
//
#include <hip/hip_runtime.h>
#include <hip/hip_bf16.h>
#include <math.h>

#define NN 8192
#define DD 64
#define TILES_SYM 2080          // 64*65/2 per symmetric combo
#define TILES_TOTAL 8256        // 2*2080 + 4096
#define TILES_PER_BLOCK 8
#define NBLOCKS (TILES_TOTAL / TILES_PER_BLOCK)   // 1032

typedef __bf16 bf16x8 __attribute__((ext_vector_type(8)));
typedef float f32x4 __attribute__((ext_vector_type(4)));

#if defined(__has_builtin)
#if __has_builtin(__builtin_amdgcn_exp2f)
#define EXP2F __builtin_amdgcn_exp2f
#endif
#endif
#ifndef EXP2F
#define EXP2F exp2f
#endif

// ws layout:
//   [0,        1048576)  Xb  bf16 [8192][64]
//   [1048576,  2097152)  Zb  bf16 [8192][64]
//   [2097152, +32768)    na  f32  [8192]   ( = -log2(e) * ||x_i||^2 )
//   [+32768,  +65536)    nb  f32  [8192]
//   [+65536,  +65548)    S   f32  [3]      (sum exp(-d2) for xx, zz, xz)

__global__ void prep_kernel(const float* __restrict__ X, const float* __restrict__ Z,
                            __hip_bfloat16* __restrict__ Xb, __hip_bfloat16* __restrict__ Zb,
                            float* __restrict__ na, float* __restrict__ nb,
                            float* __restrict__ S) {
    int gw = (blockIdx.x * blockDim.x + threadIdx.x) >> 6;  // global wave = row index in [0, 2N)
    int lane = threadIdx.x & 63;
    if (gw < 2 * NN) {
        const float* src = (gw < NN) ? (X + (size_t)gw * DD) : (Z + (size_t)(gw - NN) * DD);
        float v = src[lane];
        __hip_bfloat16 h = __float2bfloat16(v);
        float xr = __bfloat162float(h);
        __hip_bfloat16* dst = (gw < NN) ? (Xb + (size_t)gw * DD) : (Zb + (size_t)(gw - NN) * DD);
        dst[lane] = h;
        float s = xr * xr;
        #pragma unroll
        for (int off = 32; off; off >>= 1) s += __shfl_xor(s, off, 64);
        if (lane == 0) {
            if (gw < NN) na[gw] = -1.4426950408889634f * s;
            else         nb[gw - NN] = -1.4426950408889634f * s;
        }
    }
    if (blockIdx.x == 0 && threadIdx.x < 3) S[threadIdx.x] = 0.f;
}

// Flat tile enumeration over live tiles only:
//   [0, 2080)        XX, upper triangle (bj >= bi)
//   [2080, 4160)     ZZ, upper triangle
//   [4160, 8256)     XZ, full 64x64
// 8-tile chunks are combo-aligned (2080 % 8 == 0), so combo is fixed per
// block: mapping is computed ONCE per block and incremented per tile.
// B-fragments + col-norms are register double-buffered (prefetch t+1 before
// MFMA of t). Tile-level conservative bound gates the exp epilogue.
__global__ __launch_bounds__(256) void mmd_kernel(
        const __hip_bfloat16* __restrict__ Xb, const __hip_bfloat16* __restrict__ Zb,
        const float* __restrict__ na, const float* __restrict__ nb,
        float* __restrict__ S) {
    int tid = threadIdx.x;
    int wave = tid >> 6, lane = tid & 63;
    int wr = wave >> 1, wc = wave & 1;
    int lm = lane & 15;   // A-frag row / B-frag col / C col (within 16)
    int lk = lane >> 4;   // k-group of 8 / C row group of 4
    __shared__ float wsum[4];
    const float C2 = 2.8853900817779268f;  // 2*log2(e)

    // ---- map block's first tile (once) ----
    int t0 = blockIdx.x * TILES_PER_BLOCK;
    int combo, bi, bj;
    if (t0 < 2 * TILES_SYM) {
        combo = (t0 < TILES_SYM) ? 0 : 1;
        int tt = (t0 < TILES_SYM) ? t0 : t0 - TILES_SYM;
        int rr = (int)((129.0f - sqrtf(16641.0f - 8.0f * (float)tt)) * 0.5f);
        if (rr < 0) rr = 0;
        while (rr > 0 && rr * (129 - rr) / 2 > tt) --rr;
        while ((rr + 1) * (128 - rr) / 2 <= tt) ++rr;
        bi = rr;
        bj = rr + (tt - rr * (129 - rr) / 2);
    } else {
        combo = 2;
        int rem = t0 - 2 * TILES_SYM;
        bi = rem >> 6;
        bj = rem & 63;
    }
    const bool sym = (combo != 2);
    const __bf16 *A, *B;
    const float *sa, *sb;
    if (combo == 0)      { A = (const __bf16*)Xb; B = (const __bf16*)Xb; sa = na; sb = na; }
    else if (combo == 1) { A = (const __bf16*)Zb; B = (const __bf16*)Zb; sa = nb; sb = nb; }
    else                 { A = (const __bf16*)Xb; B = (const __bf16*)Zb; sa = na; sb = nb; }

    // ---- A fragments + row norms for current bi ----
    bf16x8 af[2][4];
    float nav[4][4], navrtmax[4], navmax;
    {
        int row0 = bi * 128 + wr * 64;
        #pragma unroll
        for (int ks = 0; ks < 2; ++ks)
            #pragma unroll
            for (int rt = 0; rt < 4; ++rt)
                af[ks][rt] = *(const bf16x8*)(A + (size_t)(row0 + rt * 16 + lm) * DD + ks * 32 + lk * 8);
        #pragma unroll
        for (int rt = 0; rt < 4; ++rt) {
            #pragma unroll
            for (int r = 0; r < 4; ++r) nav[rt][r] = sa[row0 + rt * 16 + lk * 4 + r];
            navrtmax[rt] = fmaxf(fmaxf(nav[rt][0], nav[rt][1]), fmaxf(nav[rt][2], nav[rt][3]));
        }
        navmax = fmaxf(fmaxf(navrtmax[0], navrtmax[1]), fmaxf(navrtmax[2], navrtmax[3]));
    }

    // ---- prefetch B for first tile ----
    bf16x8 bufB[2][2][4];   // [buf][ks][ct]
    float bufNb[2][4];
    {
        int col0 = bj * 128 + wc * 64;
        #pragma unroll
        for (int ks = 0; ks < 2; ++ks)
            #pragma unroll
            for (int ct = 0; ct < 4; ++ct)
                bufB[0][ks][ct] = *(const bf16x8*)(B + (size_t)(col0 + ct * 16 + lm) * DD + ks * 32 + lk * 8);
        #pragma unroll
        for (int ct = 0; ct < 4; ++ct) bufNb[0][ct] = sb[col0 + ct * 16 + lm];
    }

    float lsum = 0.f;

    #pragma unroll
    for (int it = 0; it < TILES_PER_BLOCK; ++it) {
        const int cur = it & 1, nxt = cur ^ 1;
        const bool last = (it + 1 == TILES_PER_BLOCK);
        bool diag = sym && (bi == bj);
        float tileScale = (sym && bj > bi) ? 2.f : 1.f;
        int row0 = bi * 128 + wr * 64;
        int col0 = bj * 128 + wc * 64;

        // next tile coords + B prefetch (independent of current tile's data)
        int nbi = bi, nbj = bj;
        if (!last) {
            nbj = bj + 1;
            if (nbj == 64) { nbi = bi + 1; nbj = sym ? nbi : 0; }
            int ncol0 = nbj * 128 + wc * 64;
            #pragma unroll
            for (int ks = 0; ks < 2; ++ks)
                #pragma unroll
                for (int ct = 0; ct < 4; ++ct)
                    bufB[nxt][ks][ct] = *(const bf16x8*)(B + (size_t)(ncol0 + ct * 16 + lm) * DD + ks * 32 + lk * 8);
            #pragma unroll
            for (int ct = 0; ct < 4; ++ct) bufNb[nxt][ct] = sb[ncol0 + ct * 16 + lm];
        }

        // ---- MFMA ----
        f32x4 acc[4][4] = {};
        #pragma unroll
        for (int ks = 0; ks < 2; ++ks)
            #pragma unroll
            for (int rt = 0; rt < 4; ++rt)
                #pragma unroll
                for (int ct = 0; ct < 4; ++ct)
                    acc[rt][ct] = __builtin_amdgcn_mfma_f32_16x16x32_bf16(
                        af[ks][rt], bufB[cur][ks][rt == rt ? ct : ct], acc[rt][ct], 0, 0, 0);

        // ---- epilogue: tile-level gate, then per-frag ----
        float nbmax = fmaxf(fmaxf(bufNb[cur][0], bufNb[cur][1]), fmaxf(bufNb[cur][2], bufNb[cur][3]));
        float gmax = -1e30f;
        #pragma unroll
        for (int rt = 0; rt < 4; ++rt)
            #pragma unroll
            for (int ct = 0; ct < 4; ++ct) {
                float m = fmaxf(fmaxf(acc[rt][ct][0], acc[rt][ct][1]),
                                fmaxf(acc[rt][ct][2], acc[rt][ct][3]));
                gmax = fmaxf(gmax, m);
            }
        float tileBound = fmaf(gmax, C2, navmax + nbmax);
        if (__any(tileBound > -30.f)) {
            #pragma unroll
            for (int rt = 0; rt < 4; ++rt) {
                #pragma unroll
                for (int ct = 0; ct < 4; ++ct) {
                    float fm = fmaxf(fmaxf(acc[rt][ct][0], acc[rt][ct][1]),
                                     fmaxf(acc[rt][ct][2], acc[rt][ct][3]));
                    float fb = fmaf(fm, C2, navrtmax[rt] + bufNb[cur][ct]);
                    if (__any(fb > -30.f)) {
                        float base = bufNb[cur][ct];
                        float a0 = fmaf(acc[rt][ct][0], C2, nav[rt][0] + base);
                        float a1 = fmaf(acc[rt][ct][1], C2, nav[rt][1] + base);
                        float a2 = fmaf(acc[rt][ct][2], C2, nav[rt][2] + base);
                        float a3 = fmaf(acc[rt][ct][3], C2, nav[rt][3] + base);
                        float e0 = EXP2F(fminf(a0, 0.f));
                        float e1 = EXP2F(fminf(a1, 0.f));
                        float e2 = EXP2F(fminf(a2, 0.f));
                        float e3 = EXP2F(fminf(a3, 0.f));
                        if (diag) {
                            int gcol = col0 + ct * 16 + lm;
                            int gr = row0 + rt * 16 + lk * 4;
                            e0 *= (gr + 0 < gcol) ? 2.f : ((gr + 0 == gcol) ? 1.f : 0.f);
                            e1 *= (gr + 1 < gcol) ? 2.f : ((gr + 1 == gcol) ? 1.f : 0.f);
                            e2 *= (gr + 2 < gcol) ? 2.f : ((gr + 2 == gcol) ? 1.f : 0.f);
                            e3 *= (gr + 3 < gcol) ? 2.f : ((gr + 3 == gcol) ? 1.f : 0.f);
                            lsum += (e0 + e1) + (e2 + e3);
                        } else {
                            lsum += tileScale * ((e0 + e1) + (e2 + e3));
                        }
                    }
                }
            }
        }

        // ---- row change: reload A (after epilogue consumed nav) ----
        if (nbi != bi) {
            int nrow0 = nbi * 128 + wr * 64;
            #pragma unroll
            for (int ks = 0; ks < 2; ++ks)
                #pragma unroll
                for (int rt = 0; rt < 4; ++rt)
                    af[ks][rt] = *(const bf16x8*)(A + (size_t)(nrow0 + rt * 16 + lm) * DD + ks * 32 + lk * 8);
            #pragma unroll
            for (int rt = 0; rt < 4; ++rt) {
                #pragma unroll
                for (int r = 0; r < 4; ++r) nav[rt][r] = sa[nrow0 + rt * 16 + lk * 4 + r];
                navrtmax[rt] = fmaxf(fmaxf(nav[rt][0], nav[rt][1]), fmaxf(nav[rt][2], nav[rt][3]));
            }
            navmax = fmaxf(fmaxf(navrtmax[0], navrtmax[1]), fmaxf(navrtmax[2], navrtmax[3]));
        }
        bi = nbi; bj = nbj;
    }

    // ---- single flush ----
    #pragma unroll
    for (int off = 32; off; off >>= 1) lsum += __shfl_xor(lsum, off, 64);
    if (lane == 0) wsum[wave] = lsum;
    __syncthreads();
    if (tid == 0) atomicAdd(&S[combo], (wsum[0] + wsum[1]) + (wsum[2] + wsum[3]));
}

__global__ void final_kernel(const float* __restrict__ S, float* __restrict__ out) {
    if (threadIdx.x == 0 && blockIdx.x == 0) {
        double inv = 1.0 / ((double)NN * (double)NN * 2.5066282746310002);  // N^2 * sqrt(2*pi)
        double mxx = (double)S[0] * inv;
        double mzz = (double)S[1] * inv;
        double mxz = (double)S[2] * inv;
        double v = log(sqrt(mxx * mzz + 1e-5) / (mxz + 1e-5));
        out[0] = (float)v;
    }
}

extern "C" void kernel_launch(void* const* d_in, const int* in_sizes, int n_in,
                              void* d_out, int out_size, void* d_ws, size_t ws_size,
                              hipStream_t stream) {
    const float* X = (const float*)d_in[0];
    const float* Z = (const float*)d_in[1];
    char* ws = (char*)d_ws;
    __hip_bfloat16* Xb = (__hip_bfloat16*)(ws);
    __hip_bfloat16* Zb = (__hip_bfloat16*)(ws + 1048576);
    float* na = (float*)(ws + 2097152);
    float* nb = (float*)(ws + 2097152 + 32768);
    float* S  = (float*)(ws + 2097152 + 65536);

    hipLaunchKernelGGL(prep_kernel, dim3((2 * NN) / 4), dim3(256), 0, stream,
                       X, Z, Xb, Zb, na, nb, S);
    hipLaunchKernelGGL(mmd_kernel, dim3(NBLOCKS), dim3(256), 0, stream, Xb, Zb, na, nb, S);
    hipLaunchKernelGGL(final_kernel, dim3(1), dim3(1), 0, stream, S, (float*)d_out);
}